// Round 2
// baseline (275.759 us; speedup 1.0000x reference)
//
#include <hip/hip_runtime.h>

#define B_SZ   32
#define LEN    2048
#define DIM    256
#define NST    64
#define OUTD   256
#define CHUNK  64
#define NCHUNK (LEN / CHUNK)     // 32
#define ROWS   (B_SZ * LEN)      // 65536

// ws layout (float offsets)
#define OFF_AT   0               // A_tilde [64][64]
#define OFF_P2   4096            // A_tilde^2
#define OFF_P64  8192            // A_tilde^64
#define OFF_MINV 12288           // Minv row-major [64][64]
#define OFF_CP   16384           // CP[o][n] = 0.1*(C@Minv), [256][64]
#define OFF_S    32768           // chunk-local final states [B][NCHUNK][64]
#define OFF_INST 98304           // chunk carry-in states    [B][NCHUNK][64]
#define OFF_V    163840          // v = x @ B^T [ROWS][64]
#define WS_FLOATS (OFF_V + (size_t)ROWS * 64)   // 4,358,144 floats = 16.6 MiB

// ---------------------------------------------------------------------------
// global -> LDS direct copy, 16B/lane. lds_base wave-uniform; HW adds lane*16.
// ---------------------------------------------------------------------------
__device__ __forceinline__ void gload16(const float* gp, float* lds_base,
                                        int lane_off_f) {
#if __has_builtin(__builtin_amdgcn_global_load_lds)
  (void)lane_off_f;
  __builtin_amdgcn_global_load_lds(
      (const __attribute__((address_space(1))) unsigned int*)gp,
      (__attribute__((address_space(3))) unsigned int*)lds_base, 16, 0, 0);
#else
  float4 tmp = *(const float4*)gp;
  *(float4*)(lds_base + lane_off_f) = tmp;
#endif
}

// dst = a @ b, all [64][68] LDS tiles, 256 threads, 4x4 reg tiles.
__device__ __forceinline__ void mm64(float* dst, const float* a, const float* b,
                                     int t) {
  const int r0 = 4 * (t >> 4), c0 = 4 * (t & 15);
  float acc[4][4] = {};
  for (int k = 0; k < 64; ++k) {
    float4 bv = *(const float4*)(b + k * 68 + c0);
#pragma unroll
    for (int i = 0; i < 4; ++i) {
      float av = a[(r0 + i) * 68 + k];
      acc[i][0] = fmaf(av, bv.x, acc[i][0]);
      acc[i][1] = fmaf(av, bv.y, acc[i][1]);
      acc[i][2] = fmaf(av, bv.z, acc[i][2]);
      acc[i][3] = fmaf(av, bv.w, acc[i][3]);
    }
  }
#pragma unroll
  for (int i = 0; i < 4; ++i)
    *(float4*)(dst + (r0 + i) * 68 + c0) =
        make_float4(acc[i][0], acc[i][1], acc[i][2], acc[i][3]);
  __syncthreads();
}

// ---------------------------------------------------------------------------
// K_A fused: block 0 = prep (GJ inverse -> AT, Minv; squarings -> AT2, AT64).
// Blocks 1..256 = v-GEMM, 256-row tile, per-wave 64x64 sub-tile, 8x8 regs.
// ---------------------------------------------------------------------------
__global__ __launch_bounds__(256, 1) void k_fused0(const float* __restrict__ A,
                                                   const float* __restrict__ Bm,
                                                   const float* __restrict__ x,
                                                   float* __restrict__ ws) {
  __shared__ __align__(16) float sh[20480];    // 80 KB
  const int t = threadIdx.x;

  if (blockIdx.x == 0) {
    float* Pa  = sh;            // [64][68]
    float* Pb  = sh + 4352;     // [64][68]
    float* rbM = sh + 8704;     // [2][64]
    float* rbI = sh + 8832;     // [2][64]
    float* cb  = sh + 8960;     // [2][64]

    const int tc = t & 63;      // column owned
    const int tr = t >> 6;      // 0..3; rows 16*tr+i
    float M[16], Iv[16];
#pragma unroll
    for (int i = 0; i < 16; ++i) {
      int r = 16 * tr + i;
      M[i] = 0.05f * A[r * 64 + tc] + (r == tc ? 1.0f : 0.0f);
      Iv[i] = (r == tc) ? 1.0f : 0.0f;
    }
    if (tr == 0) { rbM[tc] = M[0]; rbI[tc] = Iv[0]; }
    if (tc == 0)
      for (int i = 0; i < 16; ++i) cb[16 * tr + i] = M[i];
    __syncthreads();

    // ---- Gauss-Jordan, no pivoting, 1 barrier/iter ----
#pragma unroll
    for (int k = 0; k < 64; ++k) {
      const int cur = (k & 1) * 64, nxt = ((k + 1) & 1) * 64;
      float rinv = 1.0f / rbM[cur + k];
      float rM = rbM[cur + tc] * rinv;
      float rI = rbI[cur + tc] * rinv;
#pragma unroll
      for (int i = 0; i < 16; ++i) {
        int r = 16 * tr + i;
        if (r == k) { M[i] = rM; Iv[i] = rI; }
        else {
          float f = cb[cur + r];
          M[i] = fmaf(-f, rM, M[i]);
          Iv[i] = fmaf(-f, rI, Iv[i]);
        }
      }
      if (k < 63) {
        if (tr == ((k + 1) >> 4)) {
          rbM[nxt + tc] = M[(k + 1) & 15];
          rbI[nxt + tc] = Iv[(k + 1) & 15];
        }
        if (tc == k + 1)
          for (int i = 0; i < 16; ++i) cb[nxt + 16 * tr + i] = M[i];
      }
      __syncthreads();
    }

    // ---- AT = 2*Minv - I -> ws + Pa; Minv -> ws ----
#pragma unroll
    for (int i = 0; i < 16; ++i) {
      int r = 16 * tr + i;
      float at = 2.0f * Iv[i] - (r == tc ? 1.0f : 0.0f);
      ws[OFF_AT + r * 64 + tc] = at;
      ws[OFF_MINV + r * 64 + tc] = Iv[i];
      Pa[r * 68 + tc] = at;
    }
    __syncthreads();

    // ---- squarings: AT2 -> ws; AT64 -> ws ----
    mm64(Pb, Pa, Pa, t);                       // AT^2
#pragma unroll
    for (int i = 0; i < 16; ++i) {
      int r = 16 * tr + i;
      ws[OFF_P2 + r * 64 + tc] = Pb[r * 68 + tc];
    }
    mm64(Pa, Pb, Pb, t);                       // AT^4
    mm64(Pb, Pa, Pa, t);                       // AT^8
    mm64(Pa, Pb, Pb, t);                       // AT^16
    mm64(Pb, Pa, Pa, t);                       // AT^32
    mm64(Pa, Pb, Pb, t);                       // AT^64
#pragma unroll
    for (int i = 0; i < 16; ++i) {
      int r = 16 * tr + i;
      ws[OFF_P64 + r * 64 + tc] = Pa[r * 68 + tc];
    }
  } else {
    // ---- v-GEMM: 256 rows/block, wave w owns rows [64w,64w+64), 8x8 regs ---
    float* xs0 = sh;              // [256][32]
    float* xs1 = sh + 8192;
    float* bs0 = sh + 16384;      // [64][32]
    float* bs1 = sh + 18432;
    const int w = t >> 6, lane = t & 63;
    const int ro8 = lane >> 3, kq8 = lane & 7;
    const int rowbase = ((int)blockIdx.x - 1) * 256;

    auto stage = [&](int d0, float* xbuf, float* bbuf) {
      // x tile: 32 chunks (8 rows x 32 f = 1KB); wave w -> chunks 8w..8w+7
#pragma unroll
      for (int c = 0; c < 8; ++c) {
        int q = 8 * w + c;
        const float* gp = x + (size_t)(rowbase + 8 * q + ro8) * 256 + d0 +
                          4 * (kq8 ^ (q & 7));
        gload16(gp, xbuf + q * 256, lane * 4);
      }
      // B tile: 8 chunks; wave w -> chunks 2w..2w+1
#pragma unroll
      for (int c = 0; c < 2; ++c) {
        int q = 2 * w + c;
        const float* gp =
            Bm + (size_t)(8 * q + ro8) * 256 + d0 + 4 * (kq8 ^ q);
        gload16(gp, bbuf + q * 256, lane * 4);
      }
    };

    stage(0, xs0, bs0);
    const int rg = lane >> 3, mg = lane & 7;
    const int r0 = 64 * w + 8 * rg;
    const int m0 = 8 * mg;
    const int ka = 4 * rg;     // row-octet key: ((row>>3)&7)*4
    const int kb = 4 * mg;
    float acc[8][8] = {};
    float* xc = xs0; float* xn = xs1; float* bc = bs0; float* bn = bs1;
    __syncthreads();

    for (int s = 0; s < 8; ++s) {
      if (s < 7) stage((s + 1) * 32, xn, bn);
      const float* xa = xc + r0 * 32;
      const float* bb = bc + m0 * 32;
#pragma unroll
      for (int k0 = 0; k0 < 32; k0 += 4) {
        float4 a4[8], b4[8];
#pragma unroll
        for (int i = 0; i < 8; ++i)
          a4[i] = *(const float4*)(xa + i * 32 + (k0 ^ ka));
#pragma unroll
        for (int j = 0; j < 8; ++j)
          b4[j] = *(const float4*)(bb + j * 32 + (k0 ^ kb));
#pragma unroll
        for (int i = 0; i < 8; ++i)
#pragma unroll
          for (int j = 0; j < 8; ++j) {
            acc[i][j] = fmaf(a4[i].x, b4[j].x, acc[i][j]);
            acc[i][j] = fmaf(a4[i].y, b4[j].y, acc[i][j]);
            acc[i][j] = fmaf(a4[i].z, b4[j].z, acc[i][j]);
            acc[i][j] = fmaf(a4[i].w, b4[j].w, acc[i][j]);
          }
      }
      __syncthreads();
      float* tp;
      tp = xc; xc = xn; xn = tp;
      tp = bc; bc = bn; bn = tp;
    }
    float* v = ws + OFF_V;
#pragma unroll
    for (int i = 0; i < 8; ++i) {
      float* vp = v + (size_t)(rowbase + r0 + i) * 64 + m0;
      *(float4*)(vp) = make_float4(acc[i][0], acc[i][1], acc[i][2], acc[i][3]);
      *(float4*)(vp + 4) =
          make_float4(acc[i][4], acc[i][5], acc[i][6], acc[i][7]);
    }
  }
}

// ---------------------------------------------------------------------------
// Scan helpers (used by k_carry): 64x64 matvec step.
// ---------------------------------------------------------------------------
__device__ __forceinline__ void load_areg(const float* __restrict__ M, int r,
                                          int q, float areg[16]) {
  const float4* ap = (const float4*)(M + r * 64 + q * 16);
  float4 a0 = ap[0], a1 = ap[1], a2 = ap[2], a3 = ap[3];
  areg[0] = a0.x; areg[1] = a0.y; areg[2] = a0.z; areg[3] = a0.w;
  areg[4] = a1.x; areg[5] = a1.y; areg[6] = a1.z; areg[7] = a1.w;
  areg[8] = a2.x; areg[9] = a2.y; areg[10] = a2.z; areg[11] = a2.w;
  areg[12] = a3.x; areg[13] = a3.y; areg[14] = a3.z; areg[15] = a3.w;
}

__device__ __forceinline__ float matvec_step(const float areg[16],
                                             const float* __restrict__ hcur,
                                             float* __restrict__ part, int r,
                                             int q, int t) {
  float4 ha = *(const float4*)(hcur + q * 16);
  float4 hb = *(const float4*)(hcur + q * 16 + 4);
  float4 hc = *(const float4*)(hcur + q * 16 + 8);
  float4 hd = *(const float4*)(hcur + q * 16 + 12);
  float p0 = fmaf(areg[0], ha.x, fmaf(areg[4], hb.x, fmaf(areg[8], hc.x, areg[12] * hd.x)));
  float p1 = fmaf(areg[1], ha.y, fmaf(areg[5], hb.y, fmaf(areg[9], hc.y, areg[13] * hd.y)));
  float p2 = fmaf(areg[2], ha.z, fmaf(areg[6], hb.z, fmaf(areg[10], hc.z, areg[14] * hd.z)));
  float p3 = fmaf(areg[3], ha.w, fmaf(areg[7], hb.w, fmaf(areg[11], hc.w, areg[15] * hd.w)));
  part[q * 68 + r] = (p0 + p1) + (p2 + p3);
  __syncthreads();
  float s = 0.0f;
  if (t < 64) s = part[t] + part[68 + t] + part[136 + t] + part[204 + t];
  return s;
}

// ---------------------------------------------------------------------------
// K_chunk: super-stepped (stride-2) chunk scan.
//   phase=1: h0=0, emit final state to S. Extra block (x==NCHUNK,y==0): CP.
//   phase=3: h0=INST; h kept in LDS (in-place over u, XOR-swizzled), then
//            fused y-epilogue: y[64 rows][256] = H_chunk @ CP^T.
// ulds swizzle: element (row,col) stored at col ^ (row & 28).
// ---------------------------------------------------------------------------
__global__ __launch_bounds__(256) void k_chunk(float* __restrict__ ws,
                                               const float* __restrict__ Cm,
                                               float* __restrict__ y,
                                               int phase) {
  __shared__ __align__(16) float sh[11360];   // 45.4 KB
  float* ulds  = sh;           // [64][68] swizzled
  float* wbuf  = sh + 4352;    // [32][64]
  float* wpart = sh + 6400;    // [16][4][68]; epilogue: cps [64][68]
  float* partb = sh + 10752;   // [2][4][68]
  float* hcur  = sh + 11296;   // [64]
  const int t = threadIdx.x;

  if (blockIdx.x == NCHUNK) {
    // ---- CP = 0.1 * C @ Minv (one block; rest return) ----
    if (blockIdx.y != 0) return;
    float* Ms = sh;            // [64][68] Minv rows
    float* Cs = wpart;         // [64][68] C rows (one 64-o panel at a time)
#pragma unroll
    for (int i = 0; i < 4; ++i) {
      int e = 4 * (t + 256 * i);
      int kk = e >> 6, nn = e & 63;
      *(float4*)(Ms + kk * 68 + nn) = *(const float4*)(ws + OFF_MINV + e);
    }
    __syncthreads();
    const int r0 = 4 * (t >> 4), c0 = 4 * (t & 15);
    for (int ob = 0; ob < 4; ++ob) {
#pragma unroll
      for (int i = 0; i < 4; ++i) {
        int e = 4 * (t + 256 * i);
        int orow = e >> 6, kk = e & 63;
        *(float4*)(Cs + orow * 68 + kk) =
            *(const float4*)(Cm + (size_t)(64 * ob + orow) * 64 + kk);
      }
      __syncthreads();
      float acc[4][4] = {};
      for (int k = 0; k < 64; ++k) {
        float4 bv = *(const float4*)(Ms + k * 68 + c0);
#pragma unroll
        for (int i = 0; i < 4; ++i) {
          float av = Cs[(r0 + i) * 68 + k];
          acc[i][0] = fmaf(av, bv.x, acc[i][0]);
          acc[i][1] = fmaf(av, bv.y, acc[i][1]);
          acc[i][2] = fmaf(av, bv.z, acc[i][2]);
          acc[i][3] = fmaf(av, bv.w, acc[i][3]);
        }
      }
#pragma unroll
      for (int i = 0; i < 4; ++i)
        *(float4*)(ws + OFF_CP + (size_t)(64 * ob + r0 + i) * 64 + c0) =
            make_float4(0.1f * acc[i][0], 0.1f * acc[i][1], 0.1f * acc[i][2],
                        0.1f * acc[i][3]);
      __syncthreads();
    }
    return;
  }

  const int c = blockIdx.x, b = blockIdx.y;
  const int r = t & 63, q = t >> 6;
  float areg[16], areg2[16];
  load_areg(ws + OFF_AT, r, q, areg);
  load_areg(ws + OFF_P2, r, q, areg2);

  // ---- stage u (swizzled) ----
  const float* u = ws + OFF_V + (size_t)(b * LEN + c * CHUNK) * 64;
#pragma unroll
  for (int i = 0; i < 4; ++i) {
    int e = 4 * (t + 256 * i);
    int row = e >> 6, col = e & 63;
    *(float4*)(ulds + row * 68 + (col ^ (row & 28))) =
        *(const float4*)(u + e);
  }
  if (t < 64)
    hcur[t] = (phase == 3) ? ws[OFF_INST + (b * NCHUNK + c) * 64 + t] : 0.0f;
  __syncthreads();

  // ---- w precompute: w[j] = AT @ u[2j] + u[2j+1], two sweeps of 16 ----
  for (int sw = 0; sw < 2; ++sw) {
#pragma unroll
    for (int jj = 0; jj < 16; ++jj) {
      int j = 16 * sw + jj;
      int rowe = 2 * j;
      int s2 = rowe & 28;
      const float* ub = ulds + rowe * 68;
      float p = 0.0f;
#pragma unroll
      for (int cq = 0; cq < 4; ++cq) {
        float4 uv = *(const float4*)(ub + ((16 * q + 4 * cq) ^ s2));
        p = fmaf(areg[4 * cq + 0], uv.x, p);
        p = fmaf(areg[4 * cq + 1], uv.y, p);
        p = fmaf(areg[4 * cq + 2], uv.z, p);
        p = fmaf(areg[4 * cq + 3], uv.w, p);
      }
      wpart[jj * 272 + q * 68 + r] = p;
    }
    __syncthreads();
    {
      int jj = t >> 4;
      int j = 16 * sw + jj;
      int m4 = 4 * (t & 15);
      int rowo = 2 * j + 1;
      int s2o = rowo & 28;
      float4 s = make_float4(0.f, 0.f, 0.f, 0.f);
#pragma unroll
      for (int qq = 0; qq < 4; ++qq) {
        float4 pv = *(const float4*)(wpart + jj * 272 + qq * 68 + m4);
        s.x += pv.x; s.y += pv.y; s.z += pv.z; s.w += pv.w;
      }
      float4 uo = *(const float4*)(ulds + rowo * 68 + (m4 ^ s2o));
      s.x += uo.x; s.y += uo.y; s.z += uo.z; s.w += uo.w;
      *(float4*)(wbuf + j * 64 + m4) = s;
    }
    __syncthreads();
  }

  // ---- main: 32 super-steps ----
  float* part1 = partb;
  float* part2 = partb + 272;
  for (int j = 0; j < 32; ++j) {
    float4 h0 = *(const float4*)(hcur + 16 * q);
    float4 h1 = *(const float4*)(hcur + 16 * q + 4);
    float4 h2 = *(const float4*)(hcur + 16 * q + 8);
    float4 h3 = *(const float4*)(hcur + 16 * q + 12);
    float p2v;
    {
      float a0 = fmaf(areg2[0], h0.x, fmaf(areg2[4], h1.x,
                 fmaf(areg2[8], h2.x, areg2[12] * h3.x)));
      float a1 = fmaf(areg2[1], h0.y, fmaf(areg2[5], h1.y,
                 fmaf(areg2[9], h2.y, areg2[13] * h3.y)));
      float a2 = fmaf(areg2[2], h0.z, fmaf(areg2[6], h1.z,
                 fmaf(areg2[10], h2.z, areg2[14] * h3.z)));
      float a3 = fmaf(areg2[3], h0.w, fmaf(areg2[7], h1.w,
                 fmaf(areg2[11], h2.w, areg2[15] * h3.w)));
      p2v = (a0 + a1) + (a2 + a3);
    }
    part2[q * 68 + r] = p2v;
    if (phase == 3) {
      float a0 = fmaf(areg[0], h0.x, fmaf(areg[4], h1.x,
                 fmaf(areg[8], h2.x, areg[12] * h3.x)));
      float a1 = fmaf(areg[1], h0.y, fmaf(areg[5], h1.y,
                 fmaf(areg[9], h2.y, areg[13] * h3.y)));
      float a2 = fmaf(areg[2], h0.z, fmaf(areg[6], h1.z,
                 fmaf(areg[10], h2.z, areg[14] * h3.z)));
      float a3 = fmaf(areg[3], h0.w, fmaf(areg[7], h1.w,
                 fmaf(areg[11], h2.w, areg[15] * h3.w)));
      part1[q * 68 + r] = (a0 + a1) + (a2 + a3);
    }
    __syncthreads();
    if (t < 64) {
      float s2 = part2[t] + part2[68 + t] + part2[136 + t] + part2[204 + t];
      int rowe = 2 * j, rowo = 2 * j + 1;
      float ho = s2 + wbuf[j * 64 + t];
      if (phase == 3) {
        float s1 = part1[t] + part1[68 + t] + part1[136 + t] + part1[204 + t];
        float he = s1 + ulds[rowe * 68 + (t ^ (rowe & 28))];
        ulds[rowe * 68 + (t ^ (rowe & 28))] = he;
        ulds[rowo * 68 + (t ^ (rowo & 28))] = ho;
      } else if (j == 31) {
        ws[OFF_S + (b * NCHUNK + c) * 64 + t] = ho;
      }
      hcur[t] = ho;
    }
    __syncthreads();
  }

  // ---- phase-3 fused y-epilogue: y = H_chunk @ CP^T, 4 o-panels ----
  if (phase == 3) {
    float* cps = wpart;   // [64][68] swizzled
    const int r0e = 4 * (t >> 4), o0 = 4 * (t & 15);
    for (int p = 0; p < 4; ++p) {
#pragma unroll
      for (int i = 0; i < 4; ++i) {
        int e = 4 * (t + 256 * i);
        int orow = e >> 6, nn = e & 63;
        *(float4*)(cps + orow * 68 + (nn ^ (orow & 28))) =
            *(const float4*)(ws + OFF_CP + (size_t)(64 * p + orow) * 64 + nn);
      }
      __syncthreads();
      float acc[4][4] = {};
#pragma unroll
      for (int n0 = 0; n0 < 64; n0 += 4) {
        float4 a4[4], b4[4];
#pragma unroll
        for (int i = 0; i < 4; ++i)
          a4[i] = *(const float4*)(ulds + (r0e + i) * 68 +
                                   (n0 ^ ((r0e + i) & 28)));
#pragma unroll
        for (int jj = 0; jj < 4; ++jj)
          b4[jj] = *(const float4*)(cps + (o0 + jj) * 68 +
                                    (n0 ^ ((o0 + jj) & 28)));
#pragma unroll
        for (int i = 0; i < 4; ++i)
#pragma unroll
          for (int jj = 0; jj < 4; ++jj) {
            acc[i][jj] = fmaf(a4[i].x, b4[jj].x, acc[i][jj]);
            acc[i][jj] = fmaf(a4[i].y, b4[jj].y, acc[i][jj]);
            acc[i][jj] = fmaf(a4[i].z, b4[jj].z, acc[i][jj]);
            acc[i][jj] = fmaf(a4[i].w, b4[jj].w, acc[i][jj]);
          }
      }
#pragma unroll
      for (int i = 0; i < 4; ++i)
        *(float4*)(y + (size_t)(b * LEN + c * CHUNK + r0e + i) * 256 +
                   64 * p + o0) =
            make_float4(acc[i][0], acc[i][1], acc[i][2], acc[i][3]);
      __syncthreads();
    }
  }
}

// ---------------------------------------------------------------------------
// K5: sequential carry combine per batch: INST[b][0]=0,
//     INST[b][c] = AT64 @ INST[b][c-1] + S[b][c-1]
// ---------------------------------------------------------------------------
__global__ __launch_bounds__(256) void k_carry(float* __restrict__ ws) {
  __shared__ __align__(16) float hcur[64];
  __shared__ __align__(16) float part[4 * 68];
  __shared__ __align__(16) float slds[NCHUNK * 64];
  const int t = threadIdx.x;
  const int b = blockIdx.x;
  const int r = t & 63, q = t >> 6;
  float areg[16];
  load_areg(ws + OFF_P64, r, q, areg);
  for (int i = 0; i < 2; ++i) {
    int e = 4 * (t + 256 * i);
    *(float4*)(slds + e) = *(const float4*)(ws + OFF_S + b * NCHUNK * 64 + e);
  }
  if (t < 64) {
    hcur[t] = 0.0f;
    ws[OFF_INST + (b * NCHUNK) * 64 + t] = 0.0f;
  }
  __syncthreads();
  for (int c = 1; c < NCHUNK; ++c) {
    float s = matvec_step(areg, hcur, part, r, q, t);
    if (t < 64) {
      float hn = s + slds[(c - 1) * 64 + t];
      hcur[t] = hn;
      ws[OFF_INST + (b * NCHUNK + c) * 64 + t] = hn;
    }
    __syncthreads();
  }
}

// ---------------------------------------------------------------------------
extern "C" void kernel_launch(void* const* d_in, const int* in_sizes, int n_in,
                              void* d_out, int out_size, void* d_ws,
                              size_t ws_size, hipStream_t stream) {
  const float* x = (const float*)d_in[0];
  const float* A = (const float*)d_in[1];
  const float* Bm = (const float*)d_in[2];
  const float* Cm = (const float*)d_in[3];
  float* y = (float*)d_out;
  float* ws = (float*)d_ws;
  if (ws_size < (size_t)WS_FLOATS * sizeof(float)) return;  // scratch too small

  hipLaunchKernelGGL(k_fused0, dim3(1 + ROWS / 256), dim3(256), 0, stream, A,
                     Bm, x, ws);
  hipLaunchKernelGGL(k_chunk, dim3(NCHUNK + 1, B_SZ), dim3(256), 0, stream, ws,
                     Cm, y, 1);
  hipLaunchKernelGGL(k_carry, dim3(B_SZ), dim3(256), 0, stream, ws);
  hipLaunchKernelGGL(k_chunk, dim3(NCHUNK, B_SZ), dim3(256), 0, stream, ws, Cm,
                     y, 3);
}